// Round 3
// baseline (215.837 us; speedup 1.0000x reference)
//
#include <hip/hip_runtime.h>
#include <hip/hip_bf16.h>
#include <stdint.h>

#define N_NODES 4096
#define INF_ 512
#define OUTF_ 512

typedef unsigned short u16;
typedef __attribute__((ext_vector_type(8))) short bf16x8;
typedef __attribute__((ext_vector_type(4))) float f32x4;

__device__ __forceinline__ u16 f2bf(float f) {
    union { float f; uint32_t u; } v; v.f = f;
    uint32_t u = v.u;
    uint32_t r = u + 0x7FFFu + ((u >> 16) & 1u);   // round-to-nearest-even
    return (u16)(r >> 16);
}
__device__ __forceinline__ uint32_t pack2bf(float a, float b) {
    return (uint32_t)f2bf(a) | ((uint32_t)f2bf(b) << 16);
}

__device__ __forceinline__ void async16(const void* gsrc, void* ldst) {
    __builtin_amdgcn_global_load_lds(
        (const __attribute__((address_space(1))) unsigned int*)gsrc,
        (__attribute__((address_space(3))) unsigned int*)ldst,
        16, 0, 0);
}

// ---- convert X -> bf16 row-major, W -> bf16 transposed [OUTF][INF] ----
__global__ void convert_kernel(const float* __restrict__ X, const float* __restrict__ W,
                               u16* __restrict__ Xbf, u16* __restrict__ WT) {
    int tid = blockIdx.x * blockDim.x + threadIdx.x;
    if (tid < N_NODES * INF_) Xbf[tid] = f2bf(X[tid]);
    if (tid < INF_ * OUTF_) {
        int n = tid >> 9, k = tid & 511;
        WT[tid] = f2bf(W[k * OUTF_ + n]);   // WT[n][k] = W[k][n]
    }
}

// ---- gemm1: ST = (X @ W)^T bf16.  64x128 tile, BK=32, 4 waves. (verified R2) ----
__global__ __launch_bounds__(256)
void gemm_support(const u16* __restrict__ A, const u16* __restrict__ B,
                  u16* __restrict__ outT) {
    const int K = 512;
    __shared__ u16 As[64][32];
    __shared__ u16 Bs[128][32];

    const int tid  = threadIdx.x;
    const int lane = tid & 63;
    const int w    = tid >> 6;
    const int wr   = w >> 1;
    const int wc   = w & 1;
    const int brow = blockIdx.x * 64;
    const int bcol = blockIdx.y * 128;

    f32x4 acc[2][4] = {};

    const int srA = w * 16 + (lane >> 2);
    const int srB = w * 32 + (lane >> 2);
    const int sc  = (lane & 3) * 8;

    for (int kt = 0; kt < K; kt += 32) {
        __syncthreads();
        async16(&A[(long)(brow + srA) * K + kt + sc],      &As[w * 16][0]);
        async16(&B[(long)(bcol + srB) * K + kt + sc],      &Bs[w * 32][0]);
        async16(&B[(long)(bcol + srB + 16) * K + kt + sc], &Bs[w * 32 + 16][0]);
        __syncthreads();

        bf16x8 af[2], bfr[4];
#pragma unroll
        for (int m = 0; m < 2; ++m)
            af[m] = *(const bf16x8*)&As[wr * 32 + m * 16 + (lane & 15)][(lane >> 4) * 8];
#pragma unroll
        for (int n = 0; n < 4; ++n)
            bfr[n] = *(const bf16x8*)&Bs[wc * 64 + n * 16 + (lane & 15)][(lane >> 4) * 8];
#pragma unroll
        for (int m = 0; m < 2; ++m)
#pragma unroll
            for (int n = 0; n < 4; ++n)
                acc[m][n] = __builtin_amdgcn_mfma_f32_16x16x32_bf16(af[m], bfr[n], acc[m][n], 0, 0, 0);
    }

#pragma unroll
    for (int m = 0; m < 2; ++m)
#pragma unroll
        for (int n = 0; n < 4; ++n) {
            int col  = bcol + wc * 64 + n * 16 + (lane & 15);
            int row0 = brow + wr * 32 + m * 16 + (lane >> 4) * 4;
#pragma unroll
            for (int r = 0; r < 4; ++r)
                outT[(long)col * N_NODES + row0 + r] = f2bf(acc[m][n][r]);
        }
}

// ---- fused gemm2: out = reshape(E@wq) @ S + bias ----
// Each block: full-width row-stripe (16 rows x 512 cols), K=4096 in steps of 64.
// E read ONCE, directly; A-tile built in LDS (dbuf, padded); B-frags direct
// global->reg from L2-resident ST. 8 waves, wave-tile 16x64.
__global__ __launch_bounds__(512)
void fused_gemm2(const float4* __restrict__ E4, const float* __restrict__ wq,
                 const u16* __restrict__ ST, const float* __restrict__ bias,
                 float* __restrict__ out) {
    constexpr int PADW = 36;                  // u32 words/row: 16B-aligned, bank-spread
    __shared__ uint32_t As[2][16][PADW];

    const int tid   = threadIdx.x;
    const int lane  = tid & 63;
    const int w     = tid >> 6;               // 0..7
    const int brow  = blockIdx.x * 16;
    const int nbase = w * 64;

    const float w0 = wq[0], w1 = wq[1], w2 = wq[2], w3 = wq[3];

    // staging role: thread -> (row = tid>>5, 2 adjacent k elems at (tid&31)*2)
    const int srow = tid >> 5;
    const int skk  = (tid & 31) * 2;
    const float4* eptr = E4 + (long)(brow + srow) * N_NODES + skk;

    float4 ea[2], eb[2];
    {   // prologue: E(0) -> As[0]; E(1) -> slot 1 (in flight)
        float4 t0 = eptr[0];
        float4 t1 = eptr[1];
        ea[1] = eptr[64]; eb[1] = eptr[65];
        float a0 = t0.x * w0 + t0.y * w1 + t0.z * w2 + t0.w * w3;
        float a1 = t1.x * w0 + t1.y * w1 + t1.z * w2 + t1.w * w3;
        As[0][srow][skk >> 1] = pack2bf(a0, a1);
    }
    __syncthreads();

    f32x4 acc[4] = {};

    const int arow = lane & 15;
    const int ag   = lane >> 4;

    for (int s = 0; s < 64; ++s) {
        const int cur = s & 1;
        const long kt = (long)s * 64;

        // issue E(s+2) into slot cur (clamped dup at tail, harmless)
        {
            long off = (long)((s + 2 < 64) ? s + 2 : 63) * 64;
            ea[cur] = eptr[off];
            eb[cur] = eptr[off + 1];
        }

        // A-frags from LDS
        bf16x8 af0 = *(const bf16x8*)&As[cur][arow][ag * 4];
        bf16x8 af1 = *(const bf16x8*)&As[cur][arow][16 + ag * 4];

        // B-frags direct from ST (L2-resident): lane holds ST[col][k..k+7]
        bf16x8 bf_[2][4];
#pragma unroll
        for (int h = 0; h < 2; ++h)
#pragma unroll
            for (int n = 0; n < 4; ++n)
                bf_[h][n] = *(const bf16x8*)&ST[(long)(nbase + n * 16 + arow) * N_NODES
                                                + kt + h * 32 + ag * 8];

#pragma unroll
        for (int n = 0; n < 4; ++n) {
            acc[n] = __builtin_amdgcn_mfma_f32_16x16x32_bf16(af0, bf_[0][n], acc[n], 0, 0, 0);
            acc[n] = __builtin_amdgcn_mfma_f32_16x16x32_bf16(af1, bf_[1][n], acc[n], 0, 0, 0);
        }

        // stage A for step s+1 (consumes E(s+1) issued at s-1; HBM throttle lands here)
        if (s < 63) {
            float4 t0 = ea[cur ^ 1], t1 = eb[cur ^ 1];
            float a0 = t0.x * w0 + t0.y * w1 + t0.z * w2 + t0.w * w3;
            float a1 = t1.x * w0 + t1.y * w1 + t1.z * w2 + t1.w * w3;
            As[cur ^ 1][srow][skk >> 1] = pack2bf(a0, a1);
        }
        __syncthreads();
    }

    // epilogue: C/D layout col=lane&15, row=(lane>>4)*4+reg
#pragma unroll
    for (int n = 0; n < 4; ++n) {
        int col  = nbase + n * 16 + arow;
        float bv = bias[col];
#pragma unroll
        for (int r = 0; r < 4; ++r)
            out[(long)(brow + ag * 4 + r) * OUTF_ + col] = acc[n][r] + bv;
    }
}

extern "C" void kernel_launch(void* const* d_in, const int* in_sizes, int n_in,
                              void* d_out, int out_size, void* d_ws, size_t ws_size,
                              hipStream_t stream) {
    const float* X    = (const float*)d_in[0];
    // d_in[1] = adj, unused by forward
    const float* E    = (const float*)d_in[2];
    const float* W    = (const float*)d_in[3];
    const float* wq   = (const float*)d_in[4];
    const float* bias = (const float*)d_in[5];
    float* out = (float*)d_out;

    char* ws = (char*)d_ws;
    u16* ST  = (u16*)ws;                    // 512 x 4096 bf16 (support^T), 4 MB
    u16* Xbf = (u16*)(ws + (4l << 20));     // 4096 x 512 bf16
    u16* WT  = (u16*)(ws + (8l << 20));     // 512 x 512 bf16

    // 1) converts (~2us)
    convert_kernel<<<8192, 256, 0, stream>>>(X, W, Xbf, WT);
    // 2) support^T = (X @ W)^T bf16 (~5us)
    gemm_support<<<dim3(64, 4), 256, 0, stream>>>(Xbf, WT, ST);
    // 3) fused: out = reshape(E@wq) @ S + bias  (E streamed once, ~45us)
    fused_gemm2<<<256, 512, 0, stream>>>((const float4*)E, wq, ST, bias, out);
}

// Round 4
// 183.425 us; speedup vs baseline: 1.1767x; 1.1767x over previous
//
#include <hip/hip_runtime.h>
#include <hip/hip_bf16.h>
#include <stdint.h>

#define N_NODES 4096
#define INF_ 512
#define OUTF_ 512

typedef unsigned short u16;
typedef __attribute__((ext_vector_type(8))) short bf16x8;
typedef __attribute__((ext_vector_type(4))) float f32x4;

__device__ __forceinline__ u16 f2bf(float f) {
    union { float f; uint32_t u; } v; v.f = f;
    uint32_t u = v.u;
    uint32_t r = u + 0x7FFFu + ((u >> 16) & 1u);   // round-to-nearest-even
    return (u16)(r >> 16);
}

__device__ __forceinline__ void async16(const void* gsrc, void* ldst) {
    __builtin_amdgcn_global_load_lds(
        (const __attribute__((address_space(1))) unsigned int*)gsrc,
        (__attribute__((address_space(3))) unsigned int*)ldst,
        16, 0, 0);
}

// ---- convert X -> bf16 row-major, W -> bf16 transposed [OUTF][INF] ----
__global__ void convert_kernel(const float* __restrict__ X, const float* __restrict__ W,
                               u16* __restrict__ Xbf, u16* __restrict__ WT) {
    int tid = blockIdx.x * blockDim.x + threadIdx.x;
    if (tid < N_NODES * INF_) Xbf[tid] = f2bf(X[tid]);
    if (tid < INF_ * OUTF_) {
        int n = tid >> 9, k = tid & 511;
        WT[tid] = f2bf(W[k * OUTF_ + n]);   // WT[n][k] = W[k][n]
    }
}

// ---- gemm1: ST = (X @ W)^T bf16.  64x128 tile, BK=32, 4 waves. (verified R2) ----
__global__ __launch_bounds__(256)
void gemm_support(const u16* __restrict__ A, const u16* __restrict__ B,
                  u16* __restrict__ outT) {
    const int K = 512;
    __shared__ u16 As[64][32];
    __shared__ u16 Bs[128][32];

    const int tid  = threadIdx.x;
    const int lane = tid & 63;
    const int w    = tid >> 6;
    const int wr   = w >> 1;
    const int wc   = w & 1;
    const int brow = blockIdx.x * 64;
    const int bcol = blockIdx.y * 128;

    f32x4 acc[2][4] = {};

    const int srA = w * 16 + (lane >> 2);
    const int srB = w * 32 + (lane >> 2);
    const int sc  = (lane & 3) * 8;

    for (int kt = 0; kt < K; kt += 32) {
        __syncthreads();
        async16(&A[(long)(brow + srA) * K + kt + sc],      &As[w * 16][0]);
        async16(&B[(long)(bcol + srB) * K + kt + sc],      &Bs[w * 32][0]);
        async16(&B[(long)(bcol + srB + 16) * K + kt + sc], &Bs[w * 32 + 16][0]);
        __syncthreads();

        bf16x8 af[2], bfr[4];
#pragma unroll
        for (int m = 0; m < 2; ++m)
            af[m] = *(const bf16x8*)&As[wr * 32 + m * 16 + (lane & 15)][(lane >> 4) * 8];
#pragma unroll
        for (int n = 0; n < 4; ++n)
            bfr[n] = *(const bf16x8*)&Bs[wc * 64 + n * 16 + (lane & 15)][(lane >> 4) * 8];
#pragma unroll
        for (int m = 0; m < 2; ++m)
#pragma unroll
            for (int n = 0; n < 4; ++n)
                acc[m][n] = __builtin_amdgcn_mfma_f32_16x16x32_bf16(af[m], bfr[n], acc[m][n], 0, 0, 0);
    }

#pragma unroll
    for (int m = 0; m < 2; ++m)
#pragma unroll
        for (int n = 0; n < 4; ++n) {
            int col  = bcol + wc * 64 + n * 16 + (lane & 15);
            int row0 = brow + wr * 32 + m * 16 + (lane >> 4) * 4;
#pragma unroll
            for (int r = 0; r < 4; ++r)
                outT[(long)col * N_NODES + row0 + r] = f2bf(acc[m][n][r]);
        }
}

// ---- fused gemm2: out = reshape(E@wq) @ S + bias ----
// Block = 16-row full-width stripe. K=4096, BK=32, 128 steps, 8 waves.
// B (ST) staged global->LDS via global_load_lds with PRE-SWIZZLED per-lane
// source addrs (linear LDS dest); A built from E (1 float4/thread/step).
// XOR swizzle: 16B-quarter q stored at physical slot q ^ ((col>>1)&3).
__global__ __launch_bounds__(512)
void fused_gemm2(const float4* __restrict__ E4, const float* __restrict__ wq,
                 const u16* __restrict__ ST, const float* __restrict__ bias,
                 float* __restrict__ out) {
    __shared__ u16 Bs[2][512 * 32];   // 2 x 32 KB, swizzled
    __shared__ u16 As[2][16 * 32];    // 2 x 1 KB,  swizzled

    const int tid   = threadIdx.x;
    const int lane  = tid & 63;
    const int w     = tid >> 6;               // 0..7
    const int brow  = blockIdx.x * 16;
    const int nbase = w * 64;

    const float w0 = wq[0], w1 = wq[1], w2 = wq[2], w3 = wq[3];

    // --- A staging role: thread -> (row = tid>>5, k = tid&31) ---
    const int srow  = tid >> 5;
    const int sk    = tid & 31;
    const int a_off = srow * 64 + (((sk >> 3) ^ ((srow >> 1) & 3)) << 4) + (sk & 7) * 2;
    const float4* eptr = E4 + (long)(brow + srow) * N_NODES + sk;

    // --- B staging: 4 async16/wave/step; pre-swizzled global offsets (u16 units) ---
    long goffs[4];
    int  ldsb[4];
#pragma unroll
    for (int i = 0; i < 4; ++i) {
        int u   = w * 256 + i * 64 + lane;        // 16B unit index 0..2047
        int col = u >> 2;
        int q   = (u & 3) ^ ((col >> 1) & 3);     // logical k-octet
        goffs[i] = (long)col * N_NODES + q * 8;
        ldsb[i]  = (w * 256 + i * 64) * 16;       // wave-uniform LDS byte base
    }

    // --- fragment read offsets (bytes), swizzled ---
    const int arow = lane & 15;
    const int ag   = lane >> 4;
    const int qsw  = ag ^ ((arow >> 1) & 3);
    const int a_rd = (arow * 4 + qsw) * 16;
    int b_rd[4];
#pragma unroll
    for (int n = 0; n < 4; ++n)
        b_rd[n] = ((nbase + n * 16 + arow) * 4 + qsw) * 16;

    // --- prologue: stage A(0), B(0); preload E(1) ---
    float4 ecur;
    {
        float4 e0 = eptr[0];
        float a = e0.x * w0 + e0.y * w1 + e0.z * w2 + e0.w * w3;
        *(u16*)((char*)&As[0][0] + a_off) = f2bf(a);
#pragma unroll
        for (int i = 0; i < 4; ++i)
            async16(&ST[goffs[i]], (char*)&Bs[0][0] + ldsb[i]);
        ecur = eptr[32];
    }
    __syncthreads();

    f32x4 acc[4] = {};
    int cur = 0;

    for (int s = 0; s < 128; ++s) {
        // 1) A-stage for s+1 (consumes ecur = E(s+1), complete since prev barrier)
        if (s + 1 < 128) {
            float a = ecur.x * w0 + ecur.y * w1 + ecur.z * w2 + ecur.w * w3;
            *(u16*)((char*)&As[cur ^ 1][0] + a_off) = f2bf(a);
        }
        // 2) reissue E(s+2) ASAP (max issue-to-barrier gap)
        ecur = eptr[(s + 2 < 128 ? (long)(s + 2) : 127l) * 32];
        // 3) async B(s+1) -> Bs[cur^1]
        {
            const long ktn = (s + 1 < 128 ? (long)(s + 1) : 127l) * 32;
#pragma unroll
            for (int i = 0; i < 4; ++i)
                async16(&ST[goffs[i] + ktn], (char*)&Bs[cur ^ 1][0] + ldsb[i]);
        }
        // 4) compute on buffer cur
        bf16x8 af = *(const bf16x8*)((const char*)&As[cur][0] + a_rd);
        bf16x8 bfr[4];
#pragma unroll
        for (int n = 0; n < 4; ++n)
            bfr[n] = *(const bf16x8*)((const char*)&Bs[cur][0] + b_rd[n]);
#pragma unroll
        for (int n = 0; n < 4; ++n)
            acc[n] = __builtin_amdgcn_mfma_f32_16x16x32_bf16(af, bfr[n], acc[n], 0, 0, 0);
        // 5) barrier (implicit vmcnt(0)+lgkmcnt(0) drain = completion for B(s+1), E(s+2))
        __syncthreads();
        cur ^= 1;
    }

    // epilogue: C/D layout col=lane&15, row=(lane>>4)*4+reg  (verified R3)
#pragma unroll
    for (int n = 0; n < 4; ++n) {
        int col  = nbase + n * 16 + arow;
        float bv = bias[col];
#pragma unroll
        for (int r = 0; r < 4; ++r)
            out[(long)(brow + ag * 4 + r) * OUTF_ + col] = acc[n][r] + bv;
    }
}

extern "C" void kernel_launch(void* const* d_in, const int* in_sizes, int n_in,
                              void* d_out, int out_size, void* d_ws, size_t ws_size,
                              hipStream_t stream) {
    const float* X    = (const float*)d_in[0];
    // d_in[1] = adj, unused by forward
    const float* E    = (const float*)d_in[2];
    const float* W    = (const float*)d_in[3];
    const float* wq   = (const float*)d_in[4];
    const float* bias = (const float*)d_in[5];
    float* out = (float*)d_out;

    char* ws = (char*)d_ws;
    u16* ST  = (u16*)ws;                    // 512 x 4096 bf16 (support^T), 4 MB
    u16* Xbf = (u16*)(ws + (4l << 20));     // 4096 x 512 bf16
    u16* WT  = (u16*)(ws + (8l << 20));     // 512 x 512 bf16

    // 1) converts (~2us)
    convert_kernel<<<8192, 256, 0, stream>>>(X, W, Xbf, WT);
    // 2) support^T = (X @ W)^T bf16 (~5us)
    gemm_support<<<dim3(64, 4), 256, 0, stream>>>(Xbf, WT, ST);
    // 3) fused: out = reshape(E@wq) @ S + bias  (E streamed once)
    fused_gemm2<<<256, 512, 0, stream>>>((const float4*)E, wq, ST, bias, out);
}